// Round 6
// baseline (626.260 us; speedup 1.0000x reference)
//
#include <hip/hip_runtime.h>

#define NROWS   262144
#define NCODES  1024
#define DIM     64
#define NTILES  64       // 16-code MFMA tiles covering 1024 codes
#define TILEB   2048     // bytes per tile in fragment layout (2 x 1024)
#define PADT    4        // prefetch overrun pad (tiles 64..67 read, never used)

typedef _Float16 half8 __attribute__((ext_vector_type(8)));
typedef __attribute__((ext_vector_type(4))) float f32x4;

#define MFMA16(acc, a, b) acc = __builtin_amdgcn_mfma_f32_16x16x32_f16(a, b, acc, 0, 0, 0)

// ---------------------------------------------------------------------------
// Prep: arithmetic bit-identical to the validated version (sequential chain
// sums, true residual, RNE fp16). fp16 codebook stored in MFMA B-fragment
// order (validated R3 layout, TILEB=2048). E^2 plain-stored per prep-wave
// into eslots[16] (no atomicMax -> no memset); main takes max of 16 slots.
// ---------------------------------------------------------------------------
__global__ __launch_bounds__(256) void vq_prep(const float* __restrict__ cb,
                                               float* __restrict__ hcsq,
                                               char* __restrict__ stream,
                                               float* __restrict__ eslots) {
    const int k = blockIdx.x * 256 + threadIdx.x;   // 0..1023
    const float4* row = (const float4*)(cb + (size_t)k * DIM);
    char* base = stream + (size_t)(k >> 4) * TILEB + (size_t)(k & 15) * 16;
    float s = 0.f, r2 = 0.f;
#pragma unroll
    for (int i = 0; i < 8; ++i) {   // chunk i: halves i*8..i*8+7
        float4 a = row[2 * i], b = row[2 * i + 1];
        float v[8] = {a.x, a.y, a.z, a.w, b.x, b.y, b.z, b.w};
        union { half8 f; _Float16 e[8]; } uh;
#pragma unroll
        for (int j = 0; j < 8; ++j) {
            float c = v[j];
            s += c * c;                    // sequential chain (matches r4/r1)
            _Float16 h = (_Float16)c;      // RNE
            uh.e[j] = h;
            float d = c - (float)h;        // true residual
            r2 += d * d;
        }
        // chunk i -> j = i>>2 slot, q-position = i&3 (validated R3 layout)
        *(half8*)(base + ((i >> 2) << 10) + ((i & 3) << 8)) = uh.f;
    }
    hcsq[k] = 0.5f * s;
    float w = r2;
#pragma unroll
    for (int off = 1; off < 64; off <<= 1) w = fmaxf(w, __shfl_xor(w, off));
    if ((threadIdx.x & 63) == 0)
        eslots[blockIdx.x * 4 + (threadIdx.x >> 6)] = w;   // plain store
}

// ---------------------------------------------------------------------------
// Main. Same score math / margins as the validated kernels. R6 structure:
//   - R3's proven loop body (LDS nshc table, TILEB=2048 fragment stream,
//     2-deep rotating frag prefetch) -- reverts R5's regressing nh-stream.
//   - Serial-chain cut #1: nh prefetched ONE PHASE AHEAD into a register
//     (ds_read hidden under previous phase's MFMAs).
//   - Serial-chain cut #2: hi/lo MFMA chains split into two independent
//     2-deep chains (hi init -0.5||c||^2, lo init 0), merged with one add
//     in SELECT2. Rounding delta ~1e-5 << 1e-3 margin slack.
//   - 2-dispatch structure kept: eslots E, inline wave-uniform rescue
//     (validated in R5), rescue unroll capped at 4 to limit reg high-water.
// ---------------------------------------------------------------------------
#define SELECT2(h0, l0, h1, l1, tl)                                               \
    {                                                                             \
        const int _tl = (tl);                                                     \
        _Pragma("unroll")                                                         \
        for (int r = 0; r < 4; ++r) {                                             \
            float s0 = (h0)[r] + (l0)[r];                                         \
            bool g0 = s0 > best[0][r];                                            \
            second[0][r] = __builtin_amdgcn_fmed3f(s0, best[0][r], second[0][r]); \
            best[0][r] = g0 ? s0 : best[0][r];                                    \
            btile[0][r] = g0 ? _tl : btile[0][r];                                 \
            float s1 = (h1)[r] + (l1)[r];                                         \
            bool g1 = s1 > best[1][r];                                            \
            second[1][r] = __builtin_amdgcn_fmed3f(s1, best[1][r], second[1][r]); \
            best[1][r] = g1 ? s1 : best[1][r];                                    \
            btile[1][r] = g1 ? _tl : btile[1][r];                                 \
        }                                                                         \
    }

// Phase T: prefetch nh(T+1) from LDS; select pending phase T-1; run 4
// independent 2-deep MFMA chains for tile T; refill frags with tile T+2.
#define PHASE(fA, fB, h0, l0, h1, l1, oh0, ol0, oh1, ol1, nhu, nhl, TT)  \
    {                                                                    \
        nhl = nshc[((TT) + 1) * 16 + m];                                 \
        SELECT2(oh0, ol0, oh1, ol1, (TT) - 1);                           \
        h0 = (f32x4){nhu, nhu, nhu, nhu};                                \
        h1 = h0;                                                         \
        l0 = (f32x4){0.f, 0.f, 0.f, 0.f};                                \
        l1 = l0;                                                         \
        MFMA16(h0, xh[0][0], fA); MFMA16(h1, xh[1][0], fA);              \
        MFMA16(l0, xl[0][0], fA); MFMA16(l1, xl[1][0], fA);              \
        MFMA16(h0, xh[0][1], fB); MFMA16(h1, xh[1][1], fB);              \
        MFMA16(l0, xl[0][1], fB); MFMA16(l1, xl[1][1], fB);              \
        fA = *(const half8*)(gpre);                                      \
        fB = *(const half8*)(gpre + 1024);                               \
        gpre += TILEB;                                                   \
    }

__global__ __launch_bounds__(256, 4) void vq_main(const float* __restrict__ inputs,
                                                  const float* __restrict__ cb,
                                                  const float* __restrict__ hcsq,
                                                  const char* __restrict__ stream,
                                                  const float* __restrict__ eslots,
                                                  float* __restrict__ out) {
    __shared__ float nshc[NCODES + 16];   // negated 0.5||c||^2 + prefetch pad
    const int tid = threadIdx.x;
    const int lane = tid & 63;
    const int wave = tid >> 6;
    const int m = lane & 15;   // A row-in-tile / B code-in-tile / D col
    const int q = lane >> 4;   // k-quad
    const size_t rowbase = (size_t)blockIdx.x * 128 + (size_t)wave * 32;

    for (int i = tid; i < NCODES; i += 256) nshc[i] = -hcsq[i];
    if (tid < 16) nshc[NCODES + tid] = 0.f;   // pad (read by last phase, unused)

    float e2 = 0.f;
#pragma unroll
    for (int i = 0; i < 16; ++i) e2 = fmaxf(e2, eslots[i]);
    const float E = sqrtf(e2) * 1.001f;

    // A fragments (fp16 hi+lo of x) + exact row sum-of-squares for the margin.
    half8 xh[2][2], xl[2][2];
    float xsq[2];
#pragma unroll
    for (int t = 0; t < 2; ++t) {
        const float* px = inputs + (rowbase + t * 16 + m) * DIM;
        float acc = 0.f;
#pragma unroll
        for (int s = 0; s < 2; ++s) {
            const float4* p = (const float4*)(px + q * 8 + s * 32);
            float4 v0 = p[0], v1 = p[1];
            float v[8] = {v0.x, v0.y, v0.z, v0.w, v1.x, v1.y, v1.z, v1.w};
            union { half8 f; _Float16 e[8]; } uh, ul;
#pragma unroll
            for (int j = 0; j < 8; ++j) {
                acc += v[j] * v[j];
                _Float16 h = (_Float16)v[j];
                uh.e[j] = h;
                ul.e[j] = (_Float16)(v[j] - (float)h);
            }
            xh[t][s] = uh.f;
            xl[t][s] = ul.f;
        }
        acc += __shfl_xor(acc, 16);   // reduce across k-quads (same m)
        acc += __shfl_xor(acc, 32);
        xsq[t] = acc;
    }
    __syncthreads();   // nshc ready; the ONLY block barrier

    float best[2][4], second[2][4];
    int btile[2][4];
#pragma unroll
    for (int t = 0; t < 2; ++t)
#pragma unroll
        for (int r = 0; r < 4; ++r) {
            best[t][r] = -INFINITY;
            second[t][r] = -INFINITY;
            btile[t][r] = 0;
        }

    // 2-deep rotating frag prefetch over the fragment-ordered codebook.
    const char* gL = stream + (size_t)lane * 16;
    half8 f0a = *(const half8*)(gL);
    half8 f0b = *(const half8*)(gL + 1024);
    half8 f1a = *(const half8*)(gL + TILEB);
    half8 f1b = *(const half8*)(gL + TILEB + 1024);
    const char* gpre = gL + 2 * TILEB;

    float nhA = nshc[m];   // nh for tile 0
    float nhB;

    // Pending acc sets: A and B alternate; dummy -INF pending for phase -1.
    f32x4 hiA0, loA0, hiA1, loA1, hiB0, loB0, hiB1, loB1;
    hiB0 = (f32x4){-INFINITY, -INFINITY, -INFINITY, -INFINITY};
    hiB1 = hiB0;
    loB0 = (f32x4){0.f, 0.f, 0.f, 0.f};
    loB1 = loB0;

    for (int it = 0; it < 16; ++it) {
        const int T = it * 4;
        PHASE(f0a, f0b, hiA0, loA0, hiA1, loA1, hiB0, loB0, hiB1, loB1, nhA, nhB, T + 0);
        PHASE(f1a, f1b, hiB0, loB0, hiB1, loB1, hiA0, loA0, hiA1, loA1, nhB, nhA, T + 1);
        PHASE(f0a, f0b, hiA0, loA0, hiA1, loA1, hiB0, loB0, hiB1, loB1, nhA, nhB, T + 2);
        PHASE(f1a, f1b, hiB0, loB0, hiB1, loB1, hiA0, loA0, hiA1, loA1, nhB, nhA, T + 3);
    }
    SELECT2(hiB0, loB0, hiB1, loB1, NTILES - 1);   // drain last pending tile

    // Cross-lane top-2 merge (16-lane groups), min-index tie-break; gather,
    // write non-flagged rows, collect flagged rows into a per-wave bitmask.
    unsigned rowmask = 0;
#pragma unroll
    for (int t = 0; t < 2; ++t)
#pragma unroll
        for (int r = 0; r < 4; ++r) {
            float b = best[t][r], sc = second[t][r];
            int bi = btile[t][r] * 16 + m;   // reconstruct code index
#pragma unroll
            for (int off = 1; off < 16; off <<= 1) {
                float ob = __shfl_xor(b, off);
                float os = __shfl_xor(sc, off);
                int oi = __shfl_xor(bi, off);
                sc = fmaxf(fmaxf(sc, os), fminf(b, ob));
                if (ob > b || (ob == b && oi < bi)) { b = ob; bi = oi; }
            }
            size_t row = rowbase + t * 16 + q * 4 + r;
            float xs = __shfl(xsq[t], (lane & 48) | (q * 4 + r));
            float marg = 2.0f * (sqrtf(xs) * E + 1e-3f);
            bool flg = (b - sc) < marg;   // group-uniform (b, sc, xs uniform)
            if (!flg) {
                const float4* src = (const float4*)(cb + (size_t)bi * DIM);
                ((float4*)(out + row * DIM))[m] = src[m];
            } else {
                rowmask |= 1u << (t * 16 + q * 4 + r);   // ALL lanes (R5 fix)
            }
        }

    // Inline exact rescue (verbatim validated fp32 arithmetic, R5-passed).
    // xor-16/32 OR gives every lane the complete wave mask -> wave-uniform.
    rowmask |= __shfl_xor(rowmask, 16);
    rowmask |= __shfl_xor(rowmask, 32);
    while (rowmask) {
        const int rid = __builtin_ctz(rowmask);
        rowmask &= rowmask - 1;
        const size_t row = rowbase + rid;
        const int sub = lane & 15;  // dim quad
        const int g = lane >> 4;    // code within 4-group
        float4 xv = ((const float4*)(inputs + row * DIM))[sub];
        float rb = -INFINITY;
        int rbi = 0;
#pragma unroll 4
        for (int c4 = 0; c4 < NCODES / 4; ++c4) {
            int c = c4 * 4 + g;
            float4 cv = ((const float4*)(cb + (size_t)c * DIM))[sub];
            float p = xv.x * cv.x + xv.y * cv.y + xv.z * cv.z + xv.w * cv.w;
            p += __shfl_xor(p, 1);
            p += __shfl_xor(p, 2);
            p += __shfl_xor(p, 4);
            p += __shfl_xor(p, 8);
            float s = p - hcsq[c];
            if (s > rb) { rb = s; rbi = c; }
        }
#pragma unroll
        for (int off = 16; off < 64; off <<= 1) {
            float ob = __shfl_xor(rb, off);
            int oi = __shfl_xor(rbi, off);
            if (ob > rb || (ob == rb && oi < rbi)) { rb = ob; rbi = oi; }
        }
        out[row * DIM + lane] = cb[(size_t)rbi * DIM + lane];
    }
}

extern "C" void kernel_launch(void* const* d_in, const int* in_sizes, int n_in,
                              void* d_out, int out_size, void* d_ws, size_t ws_size,
                              hipStream_t stream_) {
    const float* inputs = (const float*)d_in[0];    // [262144, 64] fp32
    const float* cb = (const float*)d_in[1];        // [1024, 64] fp32
    float* out = (float*)d_out;

    // ws: hcsq f32[1024] | tile stream [68 x 2048 B] | eslots f32[16]
    char* ws = (char*)d_ws;
    float* hcsq = (float*)ws;                                       //   4 KiB
    char* strm = ws + 4096;                                         // 136 KiB
    float* eslots = (float*)(ws + 4096 + (NTILES + PADT) * TILEB);

    vq_prep<<<4, 256, 0, stream_>>>(cb, hcsq, strm, eslots);
    vq_main<<<NROWS / 128, 256, 0, stream_>>>(inputs, cb, hcsq, strm, eslots, out);
}

// Round 7
// 318.682 us; speedup vs baseline: 1.9652x; 1.9652x over previous
//
#include <hip/hip_runtime.h>

#define NROWS   262144
#define NCODES  1024
#define DIM     64
#define NTILES  64       // 16-code MFMA tiles covering 1024 codes
#define TILEB   2048     // bytes per tile in fragment layout (2 x 1024)
#define PADT    4        // prefetch overrun pad (tiles 64..67 read, never used)

typedef _Float16 half8 __attribute__((ext_vector_type(8)));
typedef __attribute__((ext_vector_type(4))) float f32x4;

#define MFMA16(acc, a, b) acc = __builtin_amdgcn_mfma_f32_16x16x32_f16(a, b, acc, 0, 0, 0)

// ---------------------------------------------------------------------------
// Prep: arithmetic bit-identical to the validated version (sequential chain
// sums, true residual, RNE fp16). fp16 codebook stored in MFMA B-fragment
// order (R3-validated layout, TILEB=2048):
//   tile T (codes T*16+m), lane = q*16+m, j in {0,1}:
//   byte addr = T*2048 + j*1024 + (q*16+m)*16  holds chunk (q+4j).
// E^2 plain-stored per prep-wave into eslots[16] (no atomicMax -> no memset);
// main takes max of the 16 slots (same E value as the atomicMax version).
// ---------------------------------------------------------------------------
__global__ __launch_bounds__(256) void vq_prep(const float* __restrict__ cb,
                                               float* __restrict__ hcsq,
                                               char* __restrict__ stream,
                                               float* __restrict__ eslots) {
    const int k = blockIdx.x * 256 + threadIdx.x;   // 0..1023
    const float4* row = (const float4*)(cb + (size_t)k * DIM);
    char* base = stream + (size_t)(k >> 4) * TILEB + (size_t)(k & 15) * 16;
    float s = 0.f, r2 = 0.f;
#pragma unroll
    for (int i = 0; i < 8; ++i) {   // chunk i: halves i*8..i*8+7
        float4 a = row[2 * i], b = row[2 * i + 1];
        float v[8] = {a.x, a.y, a.z, a.w, b.x, b.y, b.z, b.w};
        union { half8 f; _Float16 e[8]; } uh;
#pragma unroll
        for (int j = 0; j < 8; ++j) {
            float c = v[j];
            s += c * c;                    // sequential chain (matches r4/r1)
            _Float16 h = (_Float16)c;      // RNE
            uh.e[j] = h;
            float d = c - (float)h;        // true residual
            r2 += d * d;
        }
        // chunk i -> j = i>>2 slot, q-position = i&3 (validated R3 layout)
        *(half8*)(base + ((i >> 2) << 10) + ((i & 3) << 8)) = uh.f;
    }
    hcsq[k] = 0.5f * s;
    float w = r2;
#pragma unroll
    for (int off = 1; off < 64; off <<= 1) w = fmaxf(w, __shfl_xor(w, off));
    if ((threadIdx.x & 63) == 0)
        eslots[blockIdx.x * 4 + (threadIdx.x >> 6)] = w;   // plain store
}

// ---------------------------------------------------------------------------
// Main. R3's 97-us loop body VERBATIM (LDS nshc table read per-phase, 4-tile
// rotating register prefetch, lag-1 select, -hc folded into acc init).
// Only deltas vs R3: E from eslots (16 scalar loads) and the R5-validated
// inline wave-uniform exact rescue replacing the list/cnt/3rd-kernel path.
// NO hi/lo split, NO nh register rotation (R6 spilled ~950 MB to scratch),
// NO global nh stream (R5's dependent-load bubble, +147 us).
// ---------------------------------------------------------------------------
#define SELECT(aa, ab, tl)                                                        \
    {                                                                             \
        const int _tl = (tl);                                                     \
        _Pragma("unroll")                                                         \
        for (int r = 0; r < 4; ++r) {                                             \
            float s0 = (aa)[r];                                                   \
            bool g0 = s0 > best[0][r];                                            \
            second[0][r] = __builtin_amdgcn_fmed3f(s0, best[0][r], second[0][r]); \
            best[0][r] = g0 ? s0 : best[0][r];                                    \
            btile[0][r] = g0 ? _tl : btile[0][r];                                 \
            float s1 = (ab)[r];                                                   \
            bool g1 = s1 > best[1][r];                                            \
            second[1][r] = __builtin_amdgcn_fmed3f(s1, best[1][r], second[1][r]); \
            best[1][r] = g1 ? s1 : best[1][r];                                    \
            btile[1][r] = g1 ? _tl : btile[1][r];                                 \
        }                                                                         \
    }

// One tile: select the OTHER acc pair (lag-1), init this pair to -hc (LDS
// read, covered by the SELECT), 8 MFMA from fragment regs, refill frags with
// the tile 4 ahead.
#define PHASE(fA, fB, a0, a1, o0, o1, TT)                     \
    {                                                         \
        const int _T = (TT);                                  \
        float nh = nshc[_T * 16 + m];                         \
        SELECT(o0, o1, _T - 1);                               \
        a0 = (f32x4){nh, nh, nh, nh};                         \
        a1 = a0;                                              \
        MFMA16(a0, xh[0][0], fA); MFMA16(a1, xh[1][0], fA);   \
        MFMA16(a0, xh[0][1], fB); MFMA16(a1, xh[1][1], fB);   \
        MFMA16(a0, xl[0][0], fA); MFMA16(a1, xl[1][0], fA);   \
        MFMA16(a0, xl[0][1], fB); MFMA16(a1, xl[1][1], fB);   \
        fA = *(const half8*)(gpre);                           \
        fB = *(const half8*)(gpre + 1024);                    \
        gpre += TILEB;                                        \
    }

__global__ __launch_bounds__(256, 4) void vq_main(const float* __restrict__ inputs,
                                                  const float* __restrict__ cb,
                                                  const float* __restrict__ hcsq,
                                                  const char* __restrict__ stream,
                                                  const float* __restrict__ eslots,
                                                  float* __restrict__ out) {
    __shared__ float nshc[NCODES];   // negated 0.5||c||^2 (4 KB, loaded once)
    const int tid = threadIdx.x;
    const int lane = tid & 63;
    const int wave = tid >> 6;
    const int m = lane & 15;   // A row-in-tile / B code-in-tile / D col
    const int q = lane >> 4;   // k-quad
    const size_t rowbase = (size_t)blockIdx.x * 128 + (size_t)wave * 32;

    for (int i = tid; i < NCODES; i += 256) nshc[i] = -hcsq[i];

    float e2 = 0.f;
#pragma unroll
    for (int i = 0; i < 16; ++i) e2 = fmaxf(e2, eslots[i]);
    const float E = sqrtf(e2) * 1.001f;

    // A fragments (fp16 hi+lo of x) + exact row sum-of-squares for the margin.
    half8 xh[2][2], xl[2][2];
    float xsq[2];
#pragma unroll
    for (int t = 0; t < 2; ++t) {
        const float* px = inputs + (rowbase + t * 16 + m) * DIM;
        float acc = 0.f;
#pragma unroll
        for (int s = 0; s < 2; ++s) {
            const float4* p = (const float4*)(px + q * 8 + s * 32);
            float4 v0 = p[0], v1 = p[1];
            float v[8] = {v0.x, v0.y, v0.z, v0.w, v1.x, v1.y, v1.z, v1.w};
            union { half8 f; _Float16 e[8]; } uh, ul;
#pragma unroll
            for (int j = 0; j < 8; ++j) {
                acc += v[j] * v[j];
                _Float16 h = (_Float16)v[j];
                uh.e[j] = h;
                ul.e[j] = (_Float16)(v[j] - (float)h);
            }
            xh[t][s] = uh.f;
            xl[t][s] = ul.f;
        }
        acc += __shfl_xor(acc, 16);   // reduce across k-quads (same m)
        acc += __shfl_xor(acc, 32);
        xsq[t] = acc;
    }
    __syncthreads();   // nshc ready; the ONLY block barrier

    float best[2][4], second[2][4];
    int btile[2][4];
#pragma unroll
    for (int t = 0; t < 2; ++t)
#pragma unroll
        for (int r = 0; r < 4; ++r) {
            best[t][r] = -INFINITY;
            second[t][r] = -INFINITY;
            btile[t][r] = 0;
        }

    // 4-tile rotating register prefetch pipeline over the fragment-ordered
    // codebook (R3-verbatim).
    const char* gL = stream + (size_t)lane * 16;
    half8 f0a = *(const half8*)(gL);
    half8 f0b = *(const half8*)(gL + 1024);
    half8 f1a = *(const half8*)(gL + TILEB);
    half8 f1b = *(const half8*)(gL + TILEB + 1024);
    half8 f2a = *(const half8*)(gL + 2 * TILEB);
    half8 f2b = *(const half8*)(gL + 2 * TILEB + 1024);
    half8 f3a = *(const half8*)(gL + 3 * TILEB);
    half8 f3b = *(const half8*)(gL + 3 * TILEB + 1024);
    const char* gpre = gL + 4 * TILEB;

    // Lag-1 select pipeline; dummy -INF makes the first select a no-op.
    f32x4 accA0, accA1, accB0, accB1;
    accB0 = (f32x4){-INFINITY, -INFINITY, -INFINITY, -INFINITY};
    accB1 = accB0;

    for (int it = 0; it < 16; ++it) {
        const int T = it * 4;
        PHASE(f0a, f0b, accA0, accA1, accB0, accB1, T + 0);
        PHASE(f1a, f1b, accB0, accB1, accA0, accA1, T + 1);
        PHASE(f2a, f2b, accA0, accA1, accB0, accB1, T + 2);
        PHASE(f3a, f3b, accB0, accB1, accA0, accA1, T + 3);
    }
    SELECT(accB0, accB1, NTILES - 1);   // drain last pending tile

    // Cross-lane top-2 merge (16-lane groups), min-index tie-break; gather,
    // write non-flagged rows, collect flagged rows into a per-wave bitmask.
    unsigned rowmask = 0;
#pragma unroll
    for (int t = 0; t < 2; ++t)
#pragma unroll
        for (int r = 0; r < 4; ++r) {
            float b = best[t][r], sc = second[t][r];
            int bi = btile[t][r] * 16 + m;   // reconstruct code index
#pragma unroll
            for (int off = 1; off < 16; off <<= 1) {
                float ob = __shfl_xor(b, off);
                float os = __shfl_xor(sc, off);
                int oi = __shfl_xor(bi, off);
                sc = fmaxf(fmaxf(sc, os), fminf(b, ob));
                if (ob > b || (ob == b && oi < bi)) { b = ob; bi = oi; }
            }
            size_t row = rowbase + t * 16 + q * 4 + r;
            float xs = __shfl(xsq[t], (lane & 48) | (q * 4 + r));
            float marg = 2.0f * (sqrtf(xs) * E + 1e-3f);
            bool flg = (b - sc) < marg;   // group-uniform (b, sc, xs uniform)
            if (!flg) {
                const float4* src = (const float4*)(cb + (size_t)bi * DIM);
                ((float4*)(out + row * DIM))[m] = src[m];
            } else {
                rowmask |= 1u << (t * 16 + q * 4 + r);   // ALL lanes (R5 fix)
            }
        }

    // Inline exact rescue (verbatim validated fp32 arithmetic, R5-passed).
    // xor-16/32 OR gives every lane the complete wave mask -> wave-uniform.
    rowmask |= __shfl_xor(rowmask, 16);
    rowmask |= __shfl_xor(rowmask, 32);
    while (rowmask) {
        const int rid = __builtin_ctz(rowmask);
        rowmask &= rowmask - 1;
        const size_t row = rowbase + rid;
        const int sub = lane & 15;  // dim quad
        const int g = lane >> 4;    // code within 4-group
        float4 xv = ((const float4*)(inputs + row * DIM))[sub];
        float rb = -INFINITY;
        int rbi = 0;
#pragma unroll 8
        for (int c4 = 0; c4 < NCODES / 4; ++c4) {
            int c = c4 * 4 + g;
            float4 cv = ((const float4*)(cb + (size_t)c * DIM))[sub];
            float p = xv.x * cv.x + xv.y * cv.y + xv.z * cv.z + xv.w * cv.w;
            p += __shfl_xor(p, 1);
            p += __shfl_xor(p, 2);
            p += __shfl_xor(p, 4);
            p += __shfl_xor(p, 8);
            float s = p - hcsq[c];
            if (s > rb) { rb = s; rbi = c; }
        }
#pragma unroll
        for (int off = 16; off < 64; off <<= 1) {
            float ob = __shfl_xor(rb, off);
            int oi = __shfl_xor(rbi, off);
            if (ob > rb || (ob == rb && oi < rbi)) { rb = ob; rbi = oi; }
        }
        out[row * DIM + lane] = cb[(size_t)rbi * DIM + lane];
    }
}

extern "C" void kernel_launch(void* const* d_in, const int* in_sizes, int n_in,
                              void* d_out, int out_size, void* d_ws, size_t ws_size,
                              hipStream_t stream_) {
    const float* inputs = (const float*)d_in[0];    // [262144, 64] fp32
    const float* cb = (const float*)d_in[1];        // [1024, 64] fp32
    float* out = (float*)d_out;

    // ws: hcsq f32[1024] | tile stream [68 x 2048 B] | eslots f32[16]
    char* ws = (char*)d_ws;
    float* hcsq = (float*)ws;                                       //   4 KiB
    char* strm = ws + 4096;                                         // 136 KiB
    float* eslots = (float*)(ws + 4096 + (NTILES + PADT) * TILEB);

    vq_prep<<<4, 256, 0, stream_>>>(cb, hcsq, strm, eslots);
    vq_main<<<NROWS / 128, 256, 0, stream_>>>(inputs, cb, hcsq, strm, eslots, out);
}

// Round 8
// 248.269 us; speedup vs baseline: 2.5225x; 1.2836x over previous
//
#include <hip/hip_runtime.h>

#define NROWS   262144
#define NCODES  1024
#define DIM     64
#define LIST_CAP 65536u
#define NTILES  64       // 16-code MFMA tiles covering 1024 codes
#define TILEB   2048     // bytes per tile in fragment layout (2 x 1024)
#define PADT    4        // prefetch overrun pad (tiles 64..67 read, never used)

typedef _Float16 half8 __attribute__((ext_vector_type(8)));
typedef __attribute__((ext_vector_type(4))) float f32x4;

#define MFMA16(acc, a, b) acc = __builtin_amdgcn_mfma_f32_16x16x32_f16(a, b, acc, 0, 0, 0)

// ---------------------------------------------------------------------------
// Prep: arithmetic bit-identical to the validated version. fp16 codebook in
// MFMA B-fragment order (R3-validated layout). E^2 plain-stored per prep-wave
// into eslots[16]; block 0 thread 0 zeroes the rescue counter (replaces the
// memset dispatch; prep->main stream order guarantees visibility).
// ---------------------------------------------------------------------------
__global__ __launch_bounds__(256) void vq_prep(const float* __restrict__ cb,
                                               float* __restrict__ hcsq,
                                               char* __restrict__ stream,
                                               float* __restrict__ eslots,
                                               unsigned* __restrict__ cnt) {
    if (blockIdx.x == 0 && threadIdx.x == 0) *cnt = 0u;
    const int k = blockIdx.x * 256 + threadIdx.x;   // 0..1023
    const float4* row = (const float4*)(cb + (size_t)k * DIM);
    char* base = stream + (size_t)(k >> 4) * TILEB + (size_t)(k & 15) * 16;
    float s = 0.f, r2 = 0.f;
#pragma unroll
    for (int i = 0; i < 8; ++i) {   // chunk i: halves i*8..i*8+7
        float4 a = row[2 * i], b = row[2 * i + 1];
        float v[8] = {a.x, a.y, a.z, a.w, b.x, b.y, b.z, b.w};
        union { half8 f; _Float16 e[8]; } uh;
#pragma unroll
        for (int j = 0; j < 8; ++j) {
            float c = v[j];
            s += c * c;                    // sequential chain (matches r4/r1)
            _Float16 h = (_Float16)c;      // RNE
            uh.e[j] = h;
            float d = c - (float)h;        // true residual
            r2 += d * d;
        }
        // chunk i -> j = i>>2 slot, q-position = i&3 (validated R3 layout)
        *(half8*)(base + ((i >> 2) << 10) + ((i & 3) << 8)) = uh.f;
    }
    hcsq[k] = 0.5f * s;
    float w = r2;
#pragma unroll
    for (int off = 1; off < 64; off <<= 1) w = fmaxf(w, __shfl_xor(w, off));
    if ((threadIdx.x & 63) == 0)
        eslots[blockIdx.x * 4 + (threadIdx.x >> 6)] = w;   // plain store
}

// ---------------------------------------------------------------------------
// Main. R3's 97-us loop structure; one change: acc inits to 0 and -hc is
// applied in SELECT (s = acc[r] - nh) -- this is R0's validated arithmetic.
// nh ping-pongs through 2 registers: tile T's nshc ds_read issues at phase T,
// is consumed at phase T+1's SELECT -> a full phase of latency cover, and the
// acc-init -> MFMA chain no longer waits on LDS. Epilogue: R0-style list
// append + unconditional default write (inline rescue removed: R7 proved the
// register-starved epilogue context makes per-row cost ~8x the standalone
// kernel's, creating a ~148-us straggler tail).
// ---------------------------------------------------------------------------
#define SELECTN(aa, ab, nh, tl)                                                   \
    {                                                                             \
        const int _tl = (tl);                                                     \
        _Pragma("unroll")                                                         \
        for (int r = 0; r < 4; ++r) {                                             \
            float s0 = (aa)[r] - (nh);                                            \
            bool g0 = s0 > best[0][r];                                            \
            second[0][r] = __builtin_amdgcn_fmed3f(s0, best[0][r], second[0][r]); \
            best[0][r] = g0 ? s0 : best[0][r];                                    \
            btile[0][r] = g0 ? _tl : btile[0][r];                                 \
            float s1 = (ab)[r] - (nh);                                            \
            bool g1 = s1 > best[1][r];                                            \
            second[1][r] = __builtin_amdgcn_fmed3f(s1, best[1][r], second[1][r]); \
            best[1][r] = g1 ? s1 : best[1][r];                                    \
            btile[1][r] = g1 ? _tl : btile[1][r];                                 \
        }                                                                         \
    }

// Phase T: issue nh(T) ds_read into nhl; select pending tile T-1 with nhu
// (loaded last phase); zero-init accs (no LDS dependency); 8 MFMA; refill
// frags with tile T+4.
#define PHASE(fA, fB, a0, a1, o0, o1, nhl, nhu, TT)           \
    {                                                         \
        nhl = nshc[(TT) * 16 + m];                            \
        SELECTN(o0, o1, nhu, (TT) - 1);                       \
        a0 = (f32x4){0.f, 0.f, 0.f, 0.f};                     \
        a1 = a0;                                              \
        MFMA16(a0, xh[0][0], fA); MFMA16(a1, xh[1][0], fA);   \
        MFMA16(a0, xh[0][1], fB); MFMA16(a1, xh[1][1], fB);   \
        MFMA16(a0, xl[0][0], fA); MFMA16(a1, xl[1][0], fA);   \
        MFMA16(a0, xl[0][1], fB); MFMA16(a1, xl[1][1], fB);   \
        fA = *(const half8*)(gpre);                           \
        fB = *(const half8*)(gpre + 1024);                    \
        gpre += TILEB;                                        \
    }

__global__ __launch_bounds__(256, 4) void vq_main(const float* __restrict__ inputs,
                                                  const float* __restrict__ cb,
                                                  const float* __restrict__ hcsq,
                                                  const char* __restrict__ stream,
                                                  const float* __restrict__ eslots,
                                                  float* __restrict__ out,
                                                  unsigned* cnt,
                                                  unsigned* __restrict__ list) {
    __shared__ float nshc[NCODES];   // negated 0.5||c||^2 (4 KB, loaded once)
    const int tid = threadIdx.x;
    const int lane = tid & 63;
    const int wave = tid >> 6;
    const int m = lane & 15;   // A row-in-tile / B code-in-tile / D col
    const int q = lane >> 4;   // k-quad
    const size_t rowbase = (size_t)blockIdx.x * 128 + (size_t)wave * 32;

    for (int i = tid; i < NCODES; i += 256) nshc[i] = hcsq[i];   // (positive hc; SELECT subtracts)

    float e2 = 0.f;
#pragma unroll
    for (int i = 0; i < 16; ++i) e2 = fmaxf(e2, eslots[i]);
    const float E = sqrtf(e2) * 1.001f;

    // A fragments (fp16 hi+lo of x) + exact row sum-of-squares for the margin.
    half8 xh[2][2], xl[2][2];
    float xsq[2];
#pragma unroll
    for (int t = 0; t < 2; ++t) {
        const float* px = inputs + (rowbase + t * 16 + m) * DIM;
        float acc = 0.f;
#pragma unroll
        for (int s = 0; s < 2; ++s) {
            const float4* p = (const float4*)(px + q * 8 + s * 32);
            float4 v0 = p[0], v1 = p[1];
            float v[8] = {v0.x, v0.y, v0.z, v0.w, v1.x, v1.y, v1.z, v1.w};
            union { half8 f; _Float16 e[8]; } uh, ul;
#pragma unroll
            for (int j = 0; j < 8; ++j) {
                acc += v[j] * v[j];
                _Float16 h = (_Float16)v[j];
                uh.e[j] = h;
                ul.e[j] = (_Float16)(v[j] - (float)h);
            }
            xh[t][s] = uh.f;
            xl[t][s] = ul.f;
        }
        acc += __shfl_xor(acc, 16);   // reduce across k-quads (same m)
        acc += __shfl_xor(acc, 32);
        xsq[t] = acc;
    }
    __syncthreads();   // nshc ready; the ONLY block barrier

    float best[2][4], second[2][4];
    int btile[2][4];
#pragma unroll
    for (int t = 0; t < 2; ++t)
#pragma unroll
        for (int r = 0; r < 4; ++r) {
            best[t][r] = -INFINITY;
            second[t][r] = -INFINITY;
            btile[t][r] = 0;
        }

    // 4-tile rotating register prefetch pipeline over the fragment-ordered
    // codebook (R3-verbatim).
    const char* gL = stream + (size_t)lane * 16;
    half8 f0a = *(const half8*)(gL);
    half8 f0b = *(const half8*)(gL + 1024);
    half8 f1a = *(const half8*)(gL + TILEB);
    half8 f1b = *(const half8*)(gL + TILEB + 1024);
    half8 f2a = *(const half8*)(gL + 2 * TILEB);
    half8 f2b = *(const half8*)(gL + 2 * TILEB + 1024);
    half8 f3a = *(const half8*)(gL + 3 * TILEB);
    half8 f3b = *(const half8*)(gL + 3 * TILEB + 1024);
    const char* gpre = gL + 4 * TILEB;

    // nh ping-pong: nhB consumed by the phase-0 dummy select (acc=-INF, so
    // s=-INF-0=-INF: strict '>' fails, fmed3(-inf,b,s)=s -> provable no-op).
    float nhA, nhB = 0.f;

    // Lag-1 select pipeline; dummy -INF pending.
    f32x4 accA0, accA1, accB0, accB1;
    accB0 = (f32x4){-INFINITY, -INFINITY, -INFINITY, -INFINITY};
    accB1 = accB0;

    for (int it = 0; it < 16; ++it) {
        const int T = it * 4;
        PHASE(f0a, f0b, accA0, accA1, accB0, accB1, nhA, nhB, T + 0);
        PHASE(f1a, f1b, accB0, accB1, accA0, accA1, nhB, nhA, T + 1);
        PHASE(f2a, f2b, accA0, accA1, accB0, accB1, nhA, nhB, T + 2);
        PHASE(f3a, f3b, accB0, accB1, accA0, accA1, nhB, nhA, T + 3);
    }
    SELECTN(accB0, accB1, nhB, NTILES - 1);   // drain (tile 63's nh is in nhB)

    // Cross-lane top-2 merge (16-lane groups), min-index tie-break; gather,
    // write, flag near-ties (rigorous per-row margin) for exact rescue.
#pragma unroll
    for (int t = 0; t < 2; ++t)
#pragma unroll
        for (int r = 0; r < 4; ++r) {
            float b = best[t][r], sc = second[t][r];
            int bi = btile[t][r] * 16 + m;   // reconstruct code index
#pragma unroll
            for (int off = 1; off < 16; off <<= 1) {
                float ob = __shfl_xor(b, off);
                float os = __shfl_xor(sc, off);
                int oi = __shfl_xor(bi, off);
                sc = fmaxf(fmaxf(sc, os), fminf(b, ob));
                if (ob > b || (ob == b && oi < bi)) { b = ob; bi = oi; }
            }
            size_t row = rowbase + t * 16 + q * 4 + r;
            float xs = __shfl(xsq[t], (lane & 48) | (q * 4 + r));
            float marg = 2.0f * (sqrtf(xs) * E + 1e-3f);
            const float4* src = (const float4*)(cb + (size_t)bi * DIM);
            ((float4*)(out + row * DIM))[m] = src[m];
            if (m == 0 && (b - sc) < marg) {
                unsigned pos = atomicAdd(cnt, 1u);
                if (pos < LIST_CAP) list[pos] = (unsigned)row;
            }
        }
}

// ---------------------------------------------------------------------------
// Rescue: R0-verbatim (exact fp32 re-solve, validated; load-balanced across
// 2048 waves -- the register-rich standalone context keeps per-row ~2 us).
// ---------------------------------------------------------------------------
__global__ __launch_bounds__(256) void vq_rescue(const float* __restrict__ inputs,
                                                 const float* __restrict__ cb,
                                                 const float* __restrict__ hcsq,
                                                 const unsigned* cnt,
                                                 const unsigned* __restrict__ list,
                                                 float* __restrict__ out) {
    unsigned n = *cnt;
    if (n > LIST_CAP) n = LIST_CAP;
    const int lane = threadIdx.x & 63;
    const int sub = lane & 15;  // dim quad
    const int g = lane >> 4;    // code within 4-group
    unsigned gw = blockIdx.x * 4u + (threadIdx.x >> 6);
    unsigned stride = gridDim.x * 4u;
    for (unsigned e = gw; e < n; e += stride) {
        unsigned row = list[e];
        float4 xv = ((const float4*)(inputs + (size_t)row * DIM))[sub];
        float best = -INFINITY;
        int bi = 0;
#pragma unroll 8
        for (int c4 = 0; c4 < NCODES / 4; ++c4) {
            int c = c4 * 4 + g;
            float4 cv = ((const float4*)(cb + (size_t)c * DIM))[sub];
            float p = xv.x * cv.x + xv.y * cv.y + xv.z * cv.z + xv.w * cv.w;
            p += __shfl_xor(p, 1);
            p += __shfl_xor(p, 2);
            p += __shfl_xor(p, 4);
            p += __shfl_xor(p, 8);
            float s = p - hcsq[c];
            if (s > best) { best = s; bi = c; }
        }
#pragma unroll
        for (int off = 16; off < 64; off <<= 1) {
            float ob = __shfl_xor(best, off);
            int oi = __shfl_xor(bi, off);
            if (ob > best || (ob == best && oi < bi)) { best = ob; bi = oi; }
        }
        out[(size_t)row * DIM + lane] = cb[(size_t)bi * DIM + lane];
    }
}

extern "C" void kernel_launch(void* const* d_in, const int* in_sizes, int n_in,
                              void* d_out, int out_size, void* d_ws, size_t ws_size,
                              hipStream_t stream_) {
    const float* inputs = (const float*)d_in[0];    // [262144, 64] fp32
    const float* cb = (const float*)d_in[1];        // [1024, 64] fp32
    float* out = (float*)d_out;

    // ws: hcsq f32[1024] | tile stream [68 x 2048 B] | eslots f32[16] |
    //     cnt u32 | list u32[65536]   (total ~406 KB, same as R3's passing ws)
    char* ws = (char*)d_ws;
    float* hcsq = (float*)ws;                                       //   4 KiB
    char* strm = ws + 4096;                                         // 136 KiB
    char* base2 = ws + 4096 + (NTILES + PADT) * TILEB;
    float* eslots = (float*)base2;                                  //  64 B
    unsigned* cnt = (unsigned*)(base2 + 64);                        //   4 B
    unsigned* list = (unsigned*)(base2 + 256);                      // 256 KiB

    vq_prep<<<4, 256, 0, stream_>>>(cb, hcsq, strm, eslots, cnt);
    vq_main<<<NROWS / 128, 256, 0, stream_>>>(inputs, cb, hcsq, strm, eslots,
                                              out, cnt, list);
    vq_rescue<<<512, 256, 0, stream_>>>(inputs, cb, hcsq, cnt, list, out);
}